// Round 1
// baseline (587.578 us; speedup 1.0000x reference)
//
#include <hip/hip_runtime.h>
#include <math.h>

// AugmentPipe: flip -> affine(rot/scale/trans) bilinear-reflect sample ->
// brightness -> contrast -> saturation -> cutout(noise). One fused pass.
// B=64, C=3, H=W=512, float32 in/out. Memory-bound (~410 MB total traffic).

constexpr int Bn = 64;
constexpr int Cn = 3;
constexpr int Hn = 512;
constexpr int Wn = 512;
constexpr float TRANSLATE_STD = 0.125f;
constexpr float SCALE_STD = 0.2f;
constexpr int CUT_H = 256; // int(512*0.5)
constexpr int CUT_W = 256;

__device__ __forceinline__ float reflect_coord(float v, float size) {
    v = fabsf(v + 0.5f);
    v = fmodf(v, 2.0f * size);
    v = fminf(v, 2.0f * size - v);
    return fminf(fmaxf(v - 0.5f, 0.0f), size - 1.0f);
}

__global__ __launch_bounds__(256) void augment_kernel(
    const float* __restrict__ images,
    const float* __restrict__ u_angle,
    const float* __restrict__ u_scale,
    const float* __restrict__ u_trans,
    const float* __restrict__ u_bright,
    const float* __restrict__ u_contrast,
    const float* __restrict__ u_sat,
    const float* __restrict__ noise,
    const int* __restrict__ m_flip,
    const int* __restrict__ m_rot,
    const int* __restrict__ m_scale,
    const int* __restrict__ m_trans,
    const int* __restrict__ m_bright,
    const int* __restrict__ m_contrast,
    const int* __restrict__ m_sat,
    const int* __restrict__ m_cut,
    const int* __restrict__ y0p,
    const int* __restrict__ x0p,
    float* __restrict__ out)
{
    const int x = blockIdx.x * 256 + threadIdx.x;
    const int y = blockIdx.y;
    const int b = blockIdx.z;

    // Per-batch params — blockIdx.z-uniform, compiler emits scalar loads.
    const float angle = (m_rot[b] > 0) ? (u_angle[b] * 2.0f - 1.0f) * 3.14159265358979323846f : 0.0f;
    const float sc    = (m_scale[b] > 0) ? (u_scale[b] * 2.0f - 1.0f) * SCALE_STD + 1.0f : 1.0f;
    const float tr    = (m_trans[b] > 0) ? (u_trans[b] * 2.0f - 1.0f) * TRANSLATE_STD : 0.0f;
    const float bb    = (m_bright[b] > 0) ? u_bright[b] * 0.2f : 0.0f;
    const float cc    = (m_contrast[b] > 0) ? u_contrast[b] + 0.5f : 1.0f;
    const float ss    = (m_sat[b] > 0) ? u_sat[b] * 2.0f : 1.0f;
    const bool  flip  = m_flip[b] > 0;
    const bool  docut = m_cut[b] > 0;
    const int   cy0   = y0p[b];
    const int   cx0   = x0p[b];

    float saf, caf;
    __sincosf(angle, &saf, &caf);
    // __sincosf is the fast path; accuracy ~1 ulp-ish of fast sin — coordinate
    // error ~1e-6 in [-pi,pi] -> value error far below the 0.108 threshold.

    // Normalized grid (matches jnp.linspace(-1,1,512): -1 + 2*j/511)
    const float gx0 = -1.0f + (2.0f / 511.0f) * (float)x;
    const float gy0 = -1.0f + (2.0f / 511.0f) * (float)y;

    const float gx = sc * (caf * gx0 - saf * gy0) + tr;
    const float gy = sc * (saf * gx0 + caf * gy0) + tr;

    // Continuous source pixel coords
    float xx = ((gx + 1.0f) * (float)Wn - 1.0f) * 0.5f;
    float yy = ((gy + 1.0f) * (float)Hn - 1.0f) * 0.5f;
    xx = reflect_coord(xx, (float)Wn);
    yy = reflect_coord(yy, (float)Hn);

    const float x0f = floorf(xx);
    const float y0f = floorf(yy);
    const float wx = xx - x0f;
    const float wy = yy - y0f;

    int x0i = (int)fminf(fmaxf(x0f, 0.0f), (float)(Wn - 1));
    int x1i = (int)fminf(x0f + 1.0f, (float)(Wn - 1));
    int y0i = (int)fminf(fmaxf(y0f, 0.0f), (float)(Hn - 1));
    int y1i = (int)fminf(y0f + 1.0f, (float)(Hn - 1));

    // Fold the horizontal flip into the gather index: flipped[y,xi] == orig[y,W-1-xi]
    if (flip) { x0i = (Wn - 1) - x0i; x1i = (Wn - 1) - x1i; }

    const size_t plane = (size_t)Hn * Wn;
    const float* imgb = images + (size_t)b * Cn * plane;
    const int r0 = y0i * Wn;
    const int r1 = y1i * Wn;

    float vals[Cn];
    #pragma unroll
    for (int c = 0; c < Cn; ++c) {
        const float* p = imgb + (size_t)c * plane;
        const float v00 = p[r0 + x0i];
        const float v01 = p[r0 + x1i];
        const float v10 = p[r1 + x0i];
        const float v11 = p[r1 + x1i];
        const float top = v00 + wx * (v01 - v00);
        const float bot = v10 + wx * (v11 - v10);
        float v = top + wy * (bot - top);
        v = fminf(fmaxf(v + bb, -1.0f), 1.0f);   // brightness + clip
        v = fminf(fmaxf(v * cc, -1.0f), 1.0f);   // contrast + clip
        vals[c] = v;
    }

    const float gray = (vals[0] + vals[1] + vals[2]) * (1.0f / 3.0f);
    const bool cut = docut && (y >= cy0) && (y < cy0 + CUT_H) && (x >= cx0) && (x < cx0 + CUT_W);

    const size_t base = (size_t)b * Cn * plane + (size_t)y * Wn + (size_t)x;
    #pragma unroll
    for (int c = 0; c < Cn; ++c) {
        float v = gray + ss * (vals[c] - gray);
        v = fminf(fmaxf(v, -1.0f), 1.0f);
        if (cut) v = noise[base + c * plane];
        out[base + c * plane] = v;
    }
}

extern "C" void kernel_launch(void* const* d_in, const int* in_sizes, int n_in,
                              void* d_out, int out_size, void* d_ws, size_t ws_size,
                              hipStream_t stream) {
    const float* images     = (const float*)d_in[0];
    const float* u_angle    = (const float*)d_in[1];
    const float* u_scale    = (const float*)d_in[2];
    const float* u_trans    = (const float*)d_in[3];
    const float* u_bright   = (const float*)d_in[4];
    const float* u_contrast = (const float*)d_in[5];
    const float* u_sat      = (const float*)d_in[6];
    const float* noise      = (const float*)d_in[7];
    const int*   m_flip     = (const int*)d_in[8];
    const int*   m_rot      = (const int*)d_in[9];
    const int*   m_scale    = (const int*)d_in[10];
    const int*   m_trans    = (const int*)d_in[11];
    const int*   m_bright   = (const int*)d_in[12];
    const int*   m_contrast = (const int*)d_in[13];
    const int*   m_sat      = (const int*)d_in[14];
    const int*   m_cut      = (const int*)d_in[15];
    const int*   y0p        = (const int*)d_in[16];
    const int*   x0p        = (const int*)d_in[17];
    float* out = (float*)d_out;

    dim3 block(256);
    dim3 grid(Wn / 256, Hn, Bn);
    augment_kernel<<<grid, block, 0, stream>>>(
        images, u_angle, u_scale, u_trans, u_bright, u_contrast, u_sat, noise,
        m_flip, m_rot, m_scale, m_trans, m_bright, m_contrast, m_sat, m_cut,
        y0p, x0p, out);
}

// Round 2
// 511.523 us; speedup vs baseline: 1.1487x; 1.1487x over previous
//
#include <hip/hip_runtime.h>
#include <math.h>

// AugmentPipe: flip -> affine(rot/scale/trans) bilinear-reflect sample ->
// brightness -> contrast -> saturation -> cutout(noise). One fused pass.
// B=64, C=3, H=W=512, float32 in/out.
//
// R1 -> R2: bottleneck was gather transaction throughput (HBM 25%, VALU 24%,
// occ 87% => TA/L1-bound). Changes:
//   (1) 2D tiles: block 32x8, wave footprint 32x2 -> rotated gather footprint
//       ~22 rows instead of ~64 -> ~3x fewer cache-line transactions.
//   (2) x-tap pair merged into one 8B load (x1 == x0 +/- 1 except clamp edge)
//       -> 6 gather loads/pixel instead of 12.
//   (3) nontemporal stores + noise loads to preserve L2 for gather reuse.

constexpr int Bn = 64;
constexpr int Cn = 3;
constexpr int Hn = 512;
constexpr int Wn = 512;
constexpr float TRANSLATE_STD = 0.125f;
constexpr float SCALE_STD = 0.2f;
constexpr int CUT_H = 256; // int(512*0.5)
constexpr int CUT_W = 256;

typedef float f2v __attribute__((ext_vector_type(2)));

__device__ __forceinline__ f2v load2(const float* p) {
    // 8B load with only 4B alignment guarantee; gfx950 supports unaligned
    // global access so this emits global_load_dwordx2.
    f2v r;
    __builtin_memcpy(&r, p, 8);
    return r;
}

__device__ __forceinline__ float reflect_coord(float v, float size) {
    v = fabsf(v + 0.5f);
    v = fmodf(v, 2.0f * size);
    v = fminf(v, 2.0f * size - v);
    return fminf(fmaxf(v - 0.5f, 0.0f), size - 1.0f);
}

__global__ __launch_bounds__(256) void augment_kernel(
    const float* __restrict__ images,
    const float* __restrict__ u_angle,
    const float* __restrict__ u_scale,
    const float* __restrict__ u_trans,
    const float* __restrict__ u_bright,
    const float* __restrict__ u_contrast,
    const float* __restrict__ u_sat,
    const float* __restrict__ noise,
    const int* __restrict__ m_flip,
    const int* __restrict__ m_rot,
    const int* __restrict__ m_scale,
    const int* __restrict__ m_trans,
    const int* __restrict__ m_bright,
    const int* __restrict__ m_contrast,
    const int* __restrict__ m_sat,
    const int* __restrict__ m_cut,
    const int* __restrict__ y0p,
    const int* __restrict__ x0p,
    float* __restrict__ out)
{
    const int x = blockIdx.x * 32 + threadIdx.x;
    const int y = blockIdx.y * 8 + threadIdx.y;
    const int b = blockIdx.z;

    // Per-batch params — blockIdx.z-uniform => scalar loads.
    const float angle = (m_rot[b] > 0) ? (u_angle[b] * 2.0f - 1.0f) * 3.14159265358979323846f : 0.0f;
    const float sc    = (m_scale[b] > 0) ? (u_scale[b] * 2.0f - 1.0f) * SCALE_STD + 1.0f : 1.0f;
    const float tr    = (m_trans[b] > 0) ? (u_trans[b] * 2.0f - 1.0f) * TRANSLATE_STD : 0.0f;
    const float bb    = (m_bright[b] > 0) ? u_bright[b] * 0.2f : 0.0f;
    const float cc    = (m_contrast[b] > 0) ? u_contrast[b] + 0.5f : 1.0f;
    const float ss    = (m_sat[b] > 0) ? u_sat[b] * 2.0f : 1.0f;
    const bool  flip  = m_flip[b] > 0;
    const bool  docut = m_cut[b] > 0;
    const int   cy0   = y0p[b];
    const int   cx0   = x0p[b];

    float saf, caf;
    __sincosf(angle, &saf, &caf);

    // Normalized grid (jnp.linspace(-1,1,512): -1 + 2*j/511)
    const float gx0 = -1.0f + (2.0f / 511.0f) * (float)x;
    const float gy0 = -1.0f + (2.0f / 511.0f) * (float)y;

    const float gx = sc * (caf * gx0 - saf * gy0) + tr;
    const float gy = sc * (saf * gx0 + caf * gy0) + tr;

    float xx = ((gx + 1.0f) * (float)Wn - 1.0f) * 0.5f;
    float yy = ((gy + 1.0f) * (float)Hn - 1.0f) * 0.5f;
    xx = reflect_coord(xx, (float)Wn);
    yy = reflect_coord(yy, (float)Hn);

    const float x0f = floorf(xx);
    const float y0f = floorf(yy);
    const float wx = xx - x0f;
    const float wy = yy - y0f;

    int x0i = (int)fminf(fmaxf(x0f, 0.0f), (float)(Wn - 1));
    int x1i = (int)fminf(x0f + 1.0f, (float)(Wn - 1));
    const int y0i = (int)fminf(fmaxf(y0f, 0.0f), (float)(Hn - 1));
    const int y1i = (int)fminf(y0f + 1.0f, (float)(Hn - 1));

    // Fold flip into gather indices: flipped[y,xi] == orig[y, W-1-xi]
    if (flip) { x0i = (Wn - 1) - x0i; x1i = (Wn - 1) - x1i; }

    // Merge the two x-taps into one float2 load at xbase; |x0i-x1i| <= 1.
    const int xbase = min(min(x0i, x1i), Wn - 2);   // keep the 8B load in-bounds
    const bool s0 = (x0i != xbase);                 // x0i == xbase+1 ?
    const bool s1 = (x1i != xbase);

    const size_t plane = (size_t)Hn * Wn;
    const float* imgb = images + (size_t)b * Cn * plane;
    const int r0 = y0i * Wn + xbase;
    const int r1 = y1i * Wn + xbase;

    float vals[Cn];
    #pragma unroll
    for (int c = 0; c < Cn; ++c) {
        const float* p = imgb + (size_t)c * plane;
        const f2v t0 = load2(p + r0);
        const f2v t1 = load2(p + r1);
        const float v00 = s0 ? t0.y : t0.x;
        const float v01 = s1 ? t0.y : t0.x;
        const float v10 = s0 ? t1.y : t1.x;
        const float v11 = s1 ? t1.y : t1.x;
        const float top = v00 + wx * (v01 - v00);
        const float bot = v10 + wx * (v11 - v10);
        float v = top + wy * (bot - top);
        v = fminf(fmaxf(v + bb, -1.0f), 1.0f);   // brightness + clip
        v = fminf(fmaxf(v * cc, -1.0f), 1.0f);   // contrast + clip
        vals[c] = v;
    }

    const float gray = (vals[0] + vals[1] + vals[2]) * (1.0f / 3.0f);
    const bool cut = docut && (y >= cy0) && (y < cy0 + CUT_H) && (x >= cx0) && (x < cx0 + CUT_W);

    const size_t base = (size_t)b * Cn * plane + (size_t)y * Wn + (size_t)x;
    #pragma unroll
    for (int c = 0; c < Cn; ++c) {
        float v = gray + ss * (vals[c] - gray);
        v = fminf(fmaxf(v, -1.0f), 1.0f);
        if (cut) v = __builtin_nontemporal_load(&noise[base + c * plane]);
        __builtin_nontemporal_store(v, &out[base + c * plane]);
    }
}

extern "C" void kernel_launch(void* const* d_in, const int* in_sizes, int n_in,
                              void* d_out, int out_size, void* d_ws, size_t ws_size,
                              hipStream_t stream) {
    const float* images     = (const float*)d_in[0];
    const float* u_angle    = (const float*)d_in[1];
    const float* u_scale    = (const float*)d_in[2];
    const float* u_trans    = (const float*)d_in[3];
    const float* u_bright   = (const float*)d_in[4];
    const float* u_contrast = (const float*)d_in[5];
    const float* u_sat      = (const float*)d_in[6];
    const float* noise      = (const float*)d_in[7];
    const int*   m_flip     = (const int*)d_in[8];
    const int*   m_rot      = (const int*)d_in[9];
    const int*   m_scale    = (const int*)d_in[10];
    const int*   m_trans    = (const int*)d_in[11];
    const int*   m_bright   = (const int*)d_in[12];
    const int*   m_contrast = (const int*)d_in[13];
    const int*   m_sat      = (const int*)d_in[14];
    const int*   m_cut      = (const int*)d_in[15];
    const int*   y0p        = (const int*)d_in[16];
    const int*   x0p        = (const int*)d_in[17];
    float* out = (float*)d_out;

    dim3 block(32, 8);
    dim3 grid(Wn / 32, Hn / 8, Bn);
    augment_kernel<<<grid, block, 0, stream>>>(
        images, u_angle, u_scale, u_trans, u_bright, u_contrast, u_sat, noise,
        m_flip, m_rot, m_scale, m_trans, m_bright, m_contrast, m_sat, m_cut,
        y0p, x0p, out);
}